// Round 1
// baseline (77.906 us; speedup 1.0000x reference)
//
#include <hip/hip_runtime.h>
#include <hip/hip_bf16.h>
#include <math.h>

#define MARGIN_F 6.0f
// phase = pr / (REL_RANGE/PI) = pr * (PI / 0.03125)
#define PHASE_SCALE 100.53096491487338f

// ---------------------------------------------------------------------------
// K1a: partial mean-pool. grid = (16 * SG) blocks, 256 threads.
// part[(b*SG+sg)*768 + h] = sum over the sg-th group of S values of qh[b,s,h]
// ---------------------------------------------------------------------------
__global__ void k_pool(const float* __restrict__ qh, float* __restrict__ part,
                       int SG) {
    int b = blockIdx.x / SG;
    int sg = blockIdx.x % SG;
    int scount = 64 / SG;
    int t = threadIdx.x;
    const float* base = qh + ((size_t)b * 64 + (size_t)sg * scount) * 768;
    float s0 = 0.f, s1 = 0.f, s2 = 0.f;
    for (int s = 0; s < scount; ++s) {
        const float* r = base + (size_t)s * 768;
        s0 += r[t];
        s1 += r[t + 256];
        s2 += r[t + 512];
    }
    float* p = part + ((size_t)b * SG + sg) * 768;
    p[t]       = s0;
    p[t + 256] = s1;
    p[t + 512] = s2;
}

// ---------------------------------------------------------------------------
// K1b: finish mean, linear(768->18)+sigmoid, mixture -> phase -> sincos,
// head gather + complex rotate. grid = 16 blocks (one per b), 256 threads.
// rot layout in ws: rot_re[16][256] at float offset 0, rot_im at 4096.
// ---------------------------------------------------------------------------
__global__ void k_rot(const float* __restrict__ part,
                      const float* __restrict__ W, const float* __restrict__ brel,
                      const float* __restrict__ rel, const float* __restrict__ ent,
                      const int* __restrict__ hid, float* __restrict__ rot,
                      int SG) {
    __shared__ float q[768];
    __shared__ float sig[18];
    int b = blockIdx.x;
    int t = threadIdx.x;

    #pragma unroll
    for (int j = 0; j < 3; ++j) {
        int h = t + j * 256;
        float s = 0.f;
        for (int g = 0; g < SG; ++g) s += part[((size_t)b * SG + g) * 768 + h];
        q[h] = s * (1.0f / 64.0f);
    }
    __syncthreads();

    int wave = t >> 6, lane = t & 63;
    for (int r = wave; r < 18; r += 4) {
        float p = 0.f;
        for (int h = lane; h < 768; h += 64) p += q[h] * W[r * 768 + h];
        for (int off = 32; off; off >>= 1) p += __shfl_xor(p, off, 64);
        if (lane == 0) sig[r] = 1.0f / (1.0f + expf(-(p + brel[r])));
    }
    __syncthreads();

    int d = t;  // 256 threads == 256 dims
    float pr = 0.f;
    #pragma unroll
    for (int r = 0; r < 18; ++r) pr += sig[r] * rel[r * 256 + d];
    float phase = pr * PHASE_SCALE;
    float sn, cs;
    sincosf(phase, &sn, &cs);
    int h0 = hid[b];
    float reh = ent[(size_t)h0 * 512 + d];
    float imh = ent[(size_t)h0 * 512 + 256 + d];
    rot[b * 256 + d]        = reh * cs - imh * sn;  // rot_re
    rot[4096 + b * 256 + d] = reh * sn + imh * cs;  // rot_im
}

// ---------------------------------------------------------------------------
// K2: wave-per-entity distance. lane l owns d = 4l..4l+3 (float4).
// rot fragments for all 16 b in registers (128 VGPR). No LDS in hot loop.
// ---------------------------------------------------------------------------
__global__ __launch_bounds__(256) void k_dist(const float* __restrict__ ent,
                                              const float* __restrict__ rot,
                                              float* __restrict__ out, int E,
                                              int nw) {
    int lane = threadIdx.x & 63;
    int wid = blockIdx.x * 4 + (threadIdx.x >> 6);

    const float4* rre4 = (const float4*)rot;
    const float4* rim4 = (const float4*)(rot + 4096);
    float4 rre[16], rim[16];
    #pragma unroll
    for (int b = 0; b < 16; ++b) {
        rre[b] = rre4[b * 64 + lane];
        rim[b] = rim4[b * 64 + lane];
    }

    // output b index for this lane after the compaction reduce (bitrev4)
    int bout = ((lane & 1) << 3) | ((lane & 2) << 1) | ((lane & 4) >> 1) |
               ((lane & 8) >> 3);

    int e = wid;
    float4 te, ti;
    if (e < E) {
        const float4* r4 = (const float4*)(ent + (size_t)e * 512);
        te = r4[lane];
        ti = r4[64 + lane];
    }
    while (e < E) {
        int en = e + nw;
        float4 nte = make_float4(0.f, 0.f, 0.f, 0.f);
        float4 nti = nte;
        if (en < E) {  // prefetch next entity row
            const float4* r4 = (const float4*)(ent + (size_t)en * 512);
            nte = r4[lane];
            nti = r4[64 + lane];
        }

        float v[16];
        #pragma unroll
        for (int b = 0; b < 16; ++b) {
            float dx0 = rre[b].x - te.x, dy0 = rim[b].x - ti.x;
            float dx1 = rre[b].y - te.y, dy1 = rim[b].y - ti.y;
            float dx2 = rre[b].z - te.z, dy2 = rim[b].z - ti.z;
            float dx3 = rre[b].w - te.w, dy3 = rim[b].w - ti.w;
            float s0 = __builtin_amdgcn_sqrtf(dx0 * dx0 + dy0 * dy0);
            float s1 = __builtin_amdgcn_sqrtf(dx1 * dx1 + dy1 * dy1);
            float s2 = __builtin_amdgcn_sqrtf(dx2 * dx2 + dy2 * dy2);
            float s3 = __builtin_amdgcn_sqrtf(dx3 * dx3 + dy3 * dy3);
            v[b] = (s0 + s1) + (s2 + s3);
        }

        // reduce 16 values x 64 lanes -> 16 values, compaction butterfly
        #pragma unroll
        for (int i = 0; i < 8; ++i) {
            float send = (lane & 1) ? v[i] : v[i + 8];
            float recv = __shfl_xor(send, 1, 64);
            v[i] = ((lane & 1) ? v[i + 8] : v[i]) + recv;
        }
        #pragma unroll
        for (int i = 0; i < 4; ++i) {
            float send = (lane & 2) ? v[i] : v[i + 4];
            float recv = __shfl_xor(send, 2, 64);
            v[i] = ((lane & 2) ? v[i + 4] : v[i]) + recv;
        }
        #pragma unroll
        for (int i = 0; i < 2; ++i) {
            float send = (lane & 4) ? v[i] : v[i + 2];
            float recv = __shfl_xor(send, 4, 64);
            v[i] = ((lane & 4) ? v[i + 2] : v[i]) + recv;
        }
        {
            float send = (lane & 8) ? v[0] : v[1];
            float recv = __shfl_xor(send, 8, 64);
            v[0] = ((lane & 8) ? v[1] : v[0]) + recv;
        }
        v[0] += __shfl_xor(v[0], 16, 64);
        v[0] += __shfl_xor(v[0], 32, 64);

        if (lane < 16) out[(size_t)bout * E + e] = MARGIN_F - v[0];

        te = nte;
        ti = nti;
        e = en;
    }
}

extern "C" void kernel_launch(void* const* d_in, const int* in_sizes, int n_in,
                              void* d_out, int out_size, void* d_ws,
                              size_t ws_size, hipStream_t stream) {
    const float* qh   = (const float*)d_in[0];  // (16,64,768)
    const float* W    = (const float*)d_in[1];  // (18,768)
    const float* brel = (const float*)d_in[2];  // (18,)
    const float* rel  = (const float*)d_in[3];  // (18,256)
    const float* ent  = (const float*)d_in[4];  // (E,512)
    const int*   hid  = (const int*)d_in[5];    // (16,)
    float* out = (float*)d_out;

    int E = in_sizes[4] / 512;

    float* rot  = (float*)d_ws;                 // 2*16*256 floats = 32 KB
    float* part = (float*)d_ws + 2 * 16 * 256;  // partial pools

    int SG = 8;
    while (SG > 1 && (2 * 16 * 256 + 16 * (size_t)SG * 768) * 4ull > ws_size)
        SG >>= 1;

    k_pool<<<dim3(16 * SG), 256, 0, stream>>>(qh, part, SG);
    k_rot<<<dim3(16), 256, 0, stream>>>(part, W, brel, rel, ent, hid, rot, SG);

    const int NB = 1024;  // 4096 waves, grid-stride over entities
    k_dist<<<dim3(NB), 256, 0, stream>>>(ent, rot, out, E, NB * 4);
}

// Round 2
// 60.338 us; speedup vs baseline: 1.2912x; 1.2912x over previous
//
#include <hip/hip_runtime.h>
#include <hip/hip_bf16.h>
#include <math.h>

#define MARGIN_F 6.0f
// phase = pr / (REL_RANGE/PI) = pr * (PI / 0.03125)
#define PHASE_SCALE 100.53096491487338f

typedef float f32x2 __attribute__((ext_vector_type(2)));

__device__ __forceinline__ f32x2 pk_add2(f32x2 a, f32x2 b) {
    f32x2 d;
    asm("v_pk_add_f32 %0, %1, %2" : "=v"(d) : "v"(a), "v"(b));
    return d;
}
__device__ __forceinline__ f32x2 pk_mul2(f32x2 a, f32x2 b) {
    f32x2 d;
    asm("v_pk_mul_f32 %0, %1, %2" : "=v"(d) : "v"(a), "v"(b));
    return d;
}
__device__ __forceinline__ f32x2 pk_fma2(f32x2 a, f32x2 b, f32x2 c) {
    f32x2 d;
    asm("v_pk_fma_f32 %0, %1, %2, %3" : "=v"(d) : "v"(a), "v"(b), "v"(c));
    return d;
}

// ---------------------------------------------------------------------------
// K1: fused prep. grid = 16 blocks (one per b), 1024 threads (16 waves).
//  - mean-pool qh[b] (64x768) -> q[768] in LDS
//  - linear 768->18 + sigmoid (one wave per relation)
//  - mixture -> phase -> sincos -> head gather -> complex rotate
// rot layout in ws: rot_re[16][256] at float offset 0, rot_im at 4096.
// ---------------------------------------------------------------------------
__global__ void k_prep(const float* __restrict__ qh, const float* __restrict__ W,
                       const float* __restrict__ brel,
                       const float* __restrict__ rel,
                       const float* __restrict__ ent, const int* __restrict__ hid,
                       float* __restrict__ rot) {
    __shared__ float q[768];
    __shared__ float sig[18];
    int b = blockIdx.x;
    int t = threadIdx.x;

    if (t < 768) {
        float s = 0.f;
        const float* base = qh + (size_t)b * 64 * 768 + t;
        #pragma unroll 8
        for (int srow = 0; srow < 64; ++srow) s += base[(size_t)srow * 768];
        q[t] = s * (1.0f / 64.0f);
    }
    __syncthreads();

    int wave = t >> 6, lane = t & 63;
    for (int r = wave; r < 18; r += 16) {
        float p = 0.f;
        for (int h = lane; h < 768; h += 64) p += q[h] * W[r * 768 + h];
        for (int off = 32; off; off >>= 1) p += __shfl_xor(p, off, 64);
        if (lane == 0) sig[r] = 1.0f / (1.0f + expf(-(p + brel[r])));
    }
    __syncthreads();

    if (t < 256) {
        int d = t;
        float pr = 0.f;
        #pragma unroll
        for (int r = 0; r < 18; ++r) pr += sig[r] * rel[r * 256 + d];
        float phase = pr * PHASE_SCALE;
        float sn, cs;
        sincosf(phase, &sn, &cs);
        int h0 = hid[b];
        float reh = ent[(size_t)h0 * 512 + d];
        float imh = ent[(size_t)h0 * 512 + 256 + d];
        rot[b * 256 + d]        = reh * cs - imh * sn;  // rot_re
        rot[4096 + b * 256 + d] = reh * sn + imh * cs;  // rot_im
    }
}

// ---------------------------------------------------------------------------
// K2: wave-per-entity-chunk distance. lane l owns d = 4l..4l+3.
// Negated rot fragments for all 16 b in registers (128 VGPR), packed-f32 math,
// contiguous entity chunk per wave (write-combining on out rows).
// ---------------------------------------------------------------------------
__global__ __launch_bounds__(256) void k_dist(const float* __restrict__ ent,
                                              const float* __restrict__ rot,
                                              float* __restrict__ out, int E,
                                              int chunk) {
    int lane = threadIdx.x & 63;
    int wid = blockIdx.x * 4 + (threadIdx.x >> 6);

    const float4* rre4 = (const float4*)rot;
    const float4* rim4 = (const float4*)(rot + 4096);
    f32x2 nre[16][2], nim[16][2];
    #pragma unroll
    for (int b = 0; b < 16; ++b) {
        float4 r = rre4[b * 64 + lane];
        nre[b][0] = f32x2{-r.x, -r.y};
        nre[b][1] = f32x2{-r.z, -r.w};
        float4 i = rim4[b * 64 + lane];
        nim[b][0] = f32x2{-i.x, -i.y};
        nim[b][1] = f32x2{-i.z, -i.w};
    }

    // output b index for this lane after the compaction reduce (bitrev4)
    int bout = ((lane & 1) << 3) | ((lane & 2) << 1) | ((lane & 4) >> 1) |
               ((lane & 8) >> 3);

    int e0 = (int)((long long)wid * chunk);
    int e1 = min(e0 + chunk, E);
    if (e0 >= e1) return;

    const float4* r4 = (const float4*)(ent + (size_t)e0 * 512);
    float4 te = r4[lane];
    float4 ti = r4[64 + lane];

    for (int e = e0; e < e1; ++e) {
        float4 nte = make_float4(0.f, 0.f, 0.f, 0.f);
        float4 nti = nte;
        if (e + 1 < e1) {  // prefetch next entity row
            const float4* n4 = (const float4*)(ent + (size_t)(e + 1) * 512);
            nte = n4[lane];
            nti = n4[64 + lane];
        }

        f32x2 te0 = f32x2{te.x, te.y}, te1 = f32x2{te.z, te.w};
        f32x2 ti0 = f32x2{ti.x, ti.y}, ti1 = f32x2{ti.z, ti.w};

        float v[16];
        #pragma unroll
        for (int b = 0; b < 16; ++b) {
            f32x2 a0 = pk_add2(te0, nre[b][0]);  // te - rre (sign-free: squared)
            f32x2 a1 = pk_add2(te1, nre[b][1]);
            f32x2 c0 = pk_add2(ti0, nim[b][0]);
            f32x2 c1 = pk_add2(ti1, nim[b][1]);
            f32x2 m0 = pk_fma2(c0, c0, pk_mul2(a0, a0));
            f32x2 m1 = pk_fma2(c1, c1, pk_mul2(a1, a1));
            float s0 = __builtin_amdgcn_sqrtf(m0.x);
            float s1 = __builtin_amdgcn_sqrtf(m0.y);
            float s2 = __builtin_amdgcn_sqrtf(m1.x);
            float s3 = __builtin_amdgcn_sqrtf(m1.y);
            v[b] = (s0 + s1) + (s2 + s3);
        }

        // reduce 16 values x 64 lanes -> 16 values, compaction butterfly
        #pragma unroll
        for (int i = 0; i < 8; ++i) {
            float send = (lane & 1) ? v[i] : v[i + 8];
            float recv = __shfl_xor(send, 1, 64);
            v[i] = ((lane & 1) ? v[i + 8] : v[i]) + recv;
        }
        #pragma unroll
        for (int i = 0; i < 4; ++i) {
            float send = (lane & 2) ? v[i] : v[i + 4];
            float recv = __shfl_xor(send, 2, 64);
            v[i] = ((lane & 2) ? v[i + 4] : v[i]) + recv;
        }
        #pragma unroll
        for (int i = 0; i < 2; ++i) {
            float send = (lane & 4) ? v[i] : v[i + 2];
            float recv = __shfl_xor(send, 4, 64);
            v[i] = ((lane & 4) ? v[i + 2] : v[i]) + recv;
        }
        {
            float send = (lane & 8) ? v[0] : v[1];
            float recv = __shfl_xor(send, 8, 64);
            v[0] = ((lane & 8) ? v[1] : v[0]) + recv;
        }
        v[0] += __shfl_xor(v[0], 16, 64);
        v[0] += __shfl_xor(v[0], 32, 64);

        if (lane < 16) out[(size_t)bout * E + e] = MARGIN_F - v[0];

        te = nte;
        ti = nti;
    }
}

extern "C" void kernel_launch(void* const* d_in, const int* in_sizes, int n_in,
                              void* d_out, int out_size, void* d_ws,
                              size_t ws_size, hipStream_t stream) {
    const float* qh   = (const float*)d_in[0];  // (16,64,768)
    const float* W    = (const float*)d_in[1];  // (18,768)
    const float* brel = (const float*)d_in[2];  // (18,)
    const float* rel  = (const float*)d_in[3];  // (18,256)
    const float* ent  = (const float*)d_in[4];  // (E,512)
    const int*   hid  = (const int*)d_in[5];    // (16,)
    float* out = (float*)d_out;

    int E = in_sizes[4] / 512;

    float* rot = (float*)d_ws;  // 2*16*256 floats = 32 KB

    k_prep<<<dim3(16), 1024, 0, stream>>>(qh, W, brel, rel, ent, hid, rot);

    const int NB = 1024;          // 4096 waves
    int nwaves = NB * 4;
    int chunk = (E + nwaves - 1) / nwaves;  // 11 consecutive entities per wave
    k_dist<<<dim3(NB), 256, 0, stream>>>(ent, rot, out, E, chunk);
}